// Round 12
// baseline (534.730 us; speedup 1.0000x reference)
//
#include <hip/hip_runtime.h>

// h[v] = sum_{(u,v) in E} feat[u], feat: [N=100000,64] f32, E=1.2M.
// Round 12: kill the dependency chains. r7/r8/r9/r11 gathers all pinned at
// ~47us regardless of bytes (bf16 halved: no change), lines, occupancy, ILP
// -> bound by serialized dependent latency in 16 per-node while-loops/wave
// (compiler can't pipeline dynamic loops at VGPR=12). New gather: flat edge
// loop into a 128x64 LDS tile via fire-and-forget ds_add_f32 (NO loop-carried
// deps), manually unrolled x4 with named regs (rule #20) so 4 payload + 4 row
// loads are in flight per iteration. No sort phase at all.

#define NBKT_BITS 7
#define NODES_PER_BKT 128      // 1 << NBKT_BITS
#define NBKT_CAP 1024
#define BIN_CHUNK 4096
#define SRC_MASK 0x1FFFF       // 17 bits, N=100000 < 131072
#define EDGE_CAP 2048          // per-bucket capacity; mean 1534, 13-sigma margin
#define TILE_STRIDE 67         // floats; 67%32=3 de-aliases ds_add banks

// ---------- LDS-aggregated direct-slot bin (r8 shape, int4 reads) ----------
__global__ __launch_bounds__(1024) void bin_direct_kernel(
        const int* __restrict__ src, const int* __restrict__ dst,
        int* __restrict__ bcnt, int* __restrict__ binned, int E, int NB) {
    __shared__ int cnt[NBKT_CAP];
    __shared__ int base[NBKT_CAP];
    const int beg = blockIdx.x * BIN_CHUNK;
    const int end = min(E, beg + BIN_CHUNK);
    const int nE = end - beg;
    for (int i = threadIdx.x; i < NB; i += blockDim.x) cnt[i] = 0;
    __syncthreads();
    if ((nE & 3) == 0) {
        const int nv = nE >> 2;
        for (int i = threadIdx.x; i < nv; i += blockDim.x) {
            const int4 d4 = *reinterpret_cast<const int4*>(dst + beg + i * 4);
            atomicAdd(&cnt[d4.x >> NBKT_BITS], 1);
            atomicAdd(&cnt[d4.y >> NBKT_BITS], 1);
            atomicAdd(&cnt[d4.z >> NBKT_BITS], 1);
            atomicAdd(&cnt[d4.w >> NBKT_BITS], 1);
        }
    } else {
        for (int i = beg + threadIdx.x; i < end; i += blockDim.x)
            atomicAdd(&cnt[dst[i] >> NBKT_BITS], 1);
    }
    __syncthreads();
    for (int i = threadIdx.x; i < NB; i += blockDim.x) {
        const int c = cnt[i];
        base[i] = c ? atomicAdd(&bcnt[i], c) : 0;
        cnt[i] = 0;
    }
    __syncthreads();
    if ((nE & 3) == 0) {
        const int nv = nE >> 2;
        for (int i = threadIdx.x; i < nv; i += blockDim.x) {
            const int4 d4 = *reinterpret_cast<const int4*>(dst + beg + i * 4);
            const int4 s4 = *reinterpret_cast<const int4*>(src + beg + i * 4);
            {
                const int b = d4.x >> NBKT_BITS;
                const int r = atomicAdd(&cnt[b], 1);
                const int pos = base[b] + r;
                if (pos < EDGE_CAP)
                    binned[(size_t)b * EDGE_CAP + pos] = s4.x | ((d4.x & (NODES_PER_BKT - 1)) << 17);
            }
            {
                const int b = d4.y >> NBKT_BITS;
                const int r = atomicAdd(&cnt[b], 1);
                const int pos = base[b] + r;
                if (pos < EDGE_CAP)
                    binned[(size_t)b * EDGE_CAP + pos] = s4.y | ((d4.y & (NODES_PER_BKT - 1)) << 17);
            }
            {
                const int b = d4.z >> NBKT_BITS;
                const int r = atomicAdd(&cnt[b], 1);
                const int pos = base[b] + r;
                if (pos < EDGE_CAP)
                    binned[(size_t)b * EDGE_CAP + pos] = s4.z | ((d4.z & (NODES_PER_BKT - 1)) << 17);
            }
            {
                const int b = d4.w >> NBKT_BITS;
                const int r = atomicAdd(&cnt[b], 1);
                const int pos = base[b] + r;
                if (pos < EDGE_CAP)
                    binned[(size_t)b * EDGE_CAP + pos] = s4.w | ((d4.w & (NODES_PER_BKT - 1)) << 17);
            }
        }
    } else {
        for (int i = beg + threadIdx.x; i < end; i += blockDim.x) {
            const int d = dst[i];
            const int b = d >> NBKT_BITS;
            const int r = atomicAdd(&cnt[b], 1);
            const int pos = base[b] + r;
            if (pos < EDGE_CAP)
                binned[(size_t)b * EDGE_CAP + pos] = src[i] | ((d & (NODES_PER_BKT - 1)) << 17);
        }
    }
}

// ---------- chain-free LDS-tile gather, 512 threads ----------
// One block per 128-node bucket. Flat edge loop: slot s (16 lanes) handles
// edge e; lane loads float4 of feat[src] and ds_add's into tile[dl].
// Unrolled x4: 4 payload loads, then 4 row loads, then 16 ds_adds -- all
// independent, nothing waits on anything from a previous iteration.
__global__ __launch_bounds__(512) void gather_tile_kernel(
        const float* __restrict__ feat, const int* __restrict__ bcnt,
        const int* __restrict__ binned, float* __restrict__ out, int N) {
    __shared__ float tile[NODES_PER_BKT * TILE_STRIDE];  // 34304 B
    const int b = blockIdx.x;
    const int t = threadIdx.x;
    const size_t gbeg = (size_t)b * EDGE_CAP;
    const int cnt = min(bcnt[b], EDGE_CAP);

    for (int i = t; i < NODES_PER_BKT * TILE_STRIDE; i += 512) tile[i] = 0.f;
    __syncthreads();

    const int wave = t >> 6;
    const int lane = t & 63;
    const int slot = lane >> 4;   // 0..3
    const int part = lane & 15;   // float4 column group
    const int colb = part * 4;

    // Block covers 32 edges per round (8 waves x 4 slots); unroll 4 rounds.
    int e = wave * 4 + slot;
    for (; e + 96 < cnt; e += 128) {
        const int pA = binned[gbeg + e];
        const int pB = binned[gbeg + e + 32];
        const int pC = binned[gbeg + e + 64];
        const int pD = binned[gbeg + e + 96];
        const float4 vA = *reinterpret_cast<const float4*>(feat + (size_t)(pA & SRC_MASK) * 64 + colb);
        const float4 vB = *reinterpret_cast<const float4*>(feat + (size_t)(pB & SRC_MASK) * 64 + colb);
        const float4 vC = *reinterpret_cast<const float4*>(feat + (size_t)(pC & SRC_MASK) * 64 + colb);
        const float4 vD = *reinterpret_cast<const float4*>(feat + (size_t)(pD & SRC_MASK) * 64 + colb);
        float* rA = &tile[((pA >> 17) & 127) * TILE_STRIDE + colb];
        float* rB = &tile[((pB >> 17) & 127) * TILE_STRIDE + colb];
        float* rC = &tile[((pC >> 17) & 127) * TILE_STRIDE + colb];
        float* rD = &tile[((pD >> 17) & 127) * TILE_STRIDE + colb];
        atomicAdd(rA + 0, vA.x); atomicAdd(rA + 1, vA.y);
        atomicAdd(rA + 2, vA.z); atomicAdd(rA + 3, vA.w);
        atomicAdd(rB + 0, vB.x); atomicAdd(rB + 1, vB.y);
        atomicAdd(rB + 2, vB.z); atomicAdd(rB + 3, vB.w);
        atomicAdd(rC + 0, vC.x); atomicAdd(rC + 1, vC.y);
        atomicAdd(rC + 2, vC.z); atomicAdd(rC + 3, vC.w);
        atomicAdd(rD + 0, vD.x); atomicAdd(rD + 1, vD.y);
        atomicAdd(rD + 2, vD.z); atomicAdd(rD + 3, vD.w);
    }
    for (; e < cnt; e += 32) {
        const int p = binned[gbeg + e];
        const float4 v = *reinterpret_cast<const float4*>(feat + (size_t)(p & SRC_MASK) * 64 + colb);
        float* r = &tile[((p >> 17) & 127) * TILE_STRIDE + colb];
        atomicAdd(r + 0, v.x); atomicAdd(r + 1, v.y);
        atomicAdd(r + 2, v.z); atomicAdd(r + 3, v.w);
    }
    __syncthreads();

    // Flush: lane owns column c = t&63; rows strided by 8. ds_read banks
    // (67r + c)%32 span all banks; global stores coalesce per wave.
    const int node0 = b * NODES_PER_BKT;
    const int rows = min(NODES_PER_BKT, N - node0);
    const int c = t & 63;
    for (int r = (t >> 6); r < rows; r += 8)
        out[(size_t)(node0 + r) * 64 + c] = tile[r * TILE_STRIDE + c];
}

// ---------- last-resort fallback ----------
__global__ void atomic_fallback_kernel(const float* __restrict__ feat,
                                       const int* __restrict__ src,
                                       const int* __restrict__ dst,
                                       float* __restrict__ out, int E) {
    const int total = E * 16;
    int idx = blockIdx.x * blockDim.x + threadIdx.x;
    const int stride = gridDim.x * blockDim.x;
    for (int i = idx; i < total; i += stride) {
        const int e = i >> 4;
        const int part = i & 15;
        const float4 v = *reinterpret_cast<const float4*>(feat + (size_t)src[e] * 64 + part * 4);
        float* o = out + (size_t)dst[e] * 64 + part * 4;
        unsafeAtomicAdd(o + 0, v.x);
        unsafeAtomicAdd(o + 1, v.y);
        unsafeAtomicAdd(o + 2, v.z);
        unsafeAtomicAdd(o + 3, v.w);
    }
}

extern "C" void kernel_launch(void* const* d_in, const int* in_sizes, int n_in,
                              void* d_out, int out_size, void* d_ws, size_t ws_size,
                              hipStream_t stream) {
    const float* feat = (const float*)d_in[0];
    const int*   src  = (const int*)d_in[1];
    const int*   dst  = (const int*)d_in[2];
    float*       out  = (float*)d_out;
    const int E = in_sizes[1];
    const int N = out_size / 64;                          // 100000
    const int NB = (N + NODES_PER_BKT - 1) >> NBKT_BITS;  // 782
    const int binGrid = (E + BIN_CHUNK - 1) / BIN_CHUNK;  // 293

    const size_t need = ((size_t)NBKT_CAP + (size_t)NB * EDGE_CAP) * sizeof(int);
    const bool shape_ok = (NB <= NBKT_CAP) && (N <= SRC_MASK + 1);

    if (shape_ok && ws_size >= need) {
        int* bcnt   = (int*)d_ws;        // NBKT_CAP
        int* binned = bcnt + NBKT_CAP;   // NB * EDGE_CAP slots
        hipMemsetAsync(bcnt, 0, (size_t)NBKT_CAP * sizeof(int), stream);
        bin_direct_kernel<<<binGrid, 1024, 0, stream>>>(src, dst, bcnt, binned, E, NB);
        gather_tile_kernel<<<NB, 512, 0, stream>>>(feat, bcnt, binned, out, N);
    } else {
        hipMemsetAsync(out, 0, (size_t)out_size * sizeof(float), stream);
        int grid = (E * 16 + 255) / 256;
        if (grid > 4096) grid = 4096;
        atomic_fallback_kernel<<<grid, 256, 0, stream>>>(feat, src, dst, out, E);
    }
}

// Round 13
// 120.001 us; speedup vs baseline: 4.4560x; 4.4560x over previous
//
#include <hip/hip_runtime.h>

// h[v] = sum_{(u,v) in E} feat[u], feat: [N=100000,64] f32, E=1.2M.
// Round 13: ABLATION. The 47us fused gather survived 4 structural changes
// (occupancy r8, ILP r9, bytes r11, loop shape r7/r8/r11) -> stop theorizing.
// Co-launch in one graph: V1 = sort phase only, V2 = gather loop only
// (synthetic lbeg + hashed src, same random-row pattern), V0 = real kernel
// LAST (writes every d_out element, overwriting V1/V2 scratch writes).
// r12 lesson recorded: ds_add_f32 LDS atomics ~0.2 ops/cyc/CU -> never on
// the hot path (explains r4/r5/r12 all landing 420-510us).

#define NBKT_BITS 7
#define NODES_PER_BKT 128      // 1 << NBKT_BITS
#define NBKT_CAP 1024
#define BIN_CHUNK 4096
#define SRC_MASK 0x1FFFF       // 17 bits, N=100000 < 131072
#define EDGE_CAP 2048          // per-bucket capacity; mean 1534, 13-sigma margin

// ---------- LDS-aggregated direct-slot bin (int4 reads) ----------
__global__ __launch_bounds__(1024) void bin_direct_kernel(
        const int* __restrict__ src, const int* __restrict__ dst,
        int* __restrict__ bcnt, int* __restrict__ binned, int E, int NB) {
    __shared__ int cnt[NBKT_CAP];
    __shared__ int base[NBKT_CAP];
    const int beg = blockIdx.x * BIN_CHUNK;
    const int end = min(E, beg + BIN_CHUNK);
    const int nE = end - beg;
    for (int i = threadIdx.x; i < NB; i += blockDim.x) cnt[i] = 0;
    __syncthreads();
    if ((nE & 3) == 0) {
        const int nv = nE >> 2;
        for (int i = threadIdx.x; i < nv; i += blockDim.x) {
            const int4 d4 = *reinterpret_cast<const int4*>(dst + beg + i * 4);
            atomicAdd(&cnt[d4.x >> NBKT_BITS], 1);
            atomicAdd(&cnt[d4.y >> NBKT_BITS], 1);
            atomicAdd(&cnt[d4.z >> NBKT_BITS], 1);
            atomicAdd(&cnt[d4.w >> NBKT_BITS], 1);
        }
    } else {
        for (int i = beg + threadIdx.x; i < end; i += blockDim.x)
            atomicAdd(&cnt[dst[i] >> NBKT_BITS], 1);
    }
    __syncthreads();
    for (int i = threadIdx.x; i < NB; i += blockDim.x) {
        const int c = cnt[i];
        base[i] = c ? atomicAdd(&bcnt[i], c) : 0;
        cnt[i] = 0;
    }
    __syncthreads();
    if ((nE & 3) == 0) {
        const int nv = nE >> 2;
        for (int i = threadIdx.x; i < nv; i += blockDim.x) {
            const int4 d4 = *reinterpret_cast<const int4*>(dst + beg + i * 4);
            const int4 s4 = *reinterpret_cast<const int4*>(src + beg + i * 4);
            {
                const int b = d4.x >> NBKT_BITS;
                const int r = atomicAdd(&cnt[b], 1);
                const int pos = base[b] + r;
                if (pos < EDGE_CAP)
                    binned[(size_t)b * EDGE_CAP + pos] = s4.x | ((d4.x & (NODES_PER_BKT - 1)) << 17);
            }
            {
                const int b = d4.y >> NBKT_BITS;
                const int r = atomicAdd(&cnt[b], 1);
                const int pos = base[b] + r;
                if (pos < EDGE_CAP)
                    binned[(size_t)b * EDGE_CAP + pos] = s4.y | ((d4.y & (NODES_PER_BKT - 1)) << 17);
            }
            {
                const int b = d4.z >> NBKT_BITS;
                const int r = atomicAdd(&cnt[b], 1);
                const int pos = base[b] + r;
                if (pos < EDGE_CAP)
                    binned[(size_t)b * EDGE_CAP + pos] = s4.z | ((d4.z & (NODES_PER_BKT - 1)) << 17);
            }
            {
                const int b = d4.w >> NBKT_BITS;
                const int r = atomicAdd(&cnt[b], 1);
                const int pos = base[b] + r;
                if (pos < EDGE_CAP)
                    binned[(size_t)b * EDGE_CAP + pos] = s4.w | ((d4.w & (NODES_PER_BKT - 1)) << 17);
            }
        }
    } else {
        for (int i = beg + threadIdx.x; i < end; i += blockDim.x) {
            const int d = dst[i];
            const int b = d >> NBKT_BITS;
            const int r = atomicAdd(&cnt[b], 1);
            const int pos = base[b] + r;
            if (pos < EDGE_CAP)
                binned[(size_t)b * EDGE_CAP + pos] = src[i] | ((d & (NODES_PER_BKT - 1)) << 17);
        }
    }
}

// ---------- ablation gather: MODE 0 = full, 1 = sort-only, 2 = loop-only ---
template <int MODE>
__global__ __launch_bounds__(512) void gather_abl_kernel(
        const float* __restrict__ feat, const int* __restrict__ bcnt,
        const int* __restrict__ binned, float* __restrict__ out, int N) {
    __shared__ int lsort[EDGE_CAP];
    __shared__ int lbeg[NODES_PER_BKT + 1];
    __shared__ int lcur[NODES_PER_BKT];
    __shared__ int lcnt[NODES_PER_BKT];
    const int b = blockIdx.x;
    const int t = threadIdx.x;
    const size_t gbeg = (size_t)b * EDGE_CAP;
    const int cnt = min(bcnt[b], EDGE_CAP);
    const int node0 = b * NODES_PER_BKT;

    if (MODE != 2) {
        // ---- phase A: binned loads + LDS histogram ----
        if (t < NODES_PER_BKT) lcnt[t] = 0;
        __syncthreads();
        int p0 = -1, p1 = -1, p2 = -1, p3 = -1;
        if (t < cnt)        { p0 = binned[gbeg + t];        atomicAdd(&lcnt[(p0 >> 17) & 127], 1); }
        if (t + 512 < cnt)  { p1 = binned[gbeg + t + 512];  atomicAdd(&lcnt[(p1 >> 17) & 127], 1); }
        if (t + 1024 < cnt) { p2 = binned[gbeg + t + 1024]; atomicAdd(&lcnt[(p2 >> 17) & 127], 1); }
        if (t + 1536 < cnt) { p3 = binned[gbeg + t + 1536]; atomicAdd(&lcnt[(p3 >> 17) & 127], 1); }
        __syncthreads();
        // ---- phase B: wave-0 scan ----
        if (t < 64) {
            const int a = lcnt[2 * t];
            const int c = lcnt[2 * t + 1];
            int s = a + c;
            for (int off = 1; off < 64; off <<= 1) {
                const int u = __shfl_up(s, off);
                if (t >= off) s += u;
            }
            const int ex = s - (a + c);
            lbeg[2 * t] = ex;         lcur[2 * t] = ex;
            lbeg[2 * t + 1] = ex + a; lcur[2 * t + 1] = ex + a;
            if (t == 63) lbeg[NODES_PER_BKT] = s;
        }
        __syncthreads();
        // ---- phase C: LDS scatter ----
        if (p0 >= 0) { const int r = atomicAdd(&lcur[(p0 >> 17) & 127], 1); lsort[r] = p0 & SRC_MASK; }
        if (p1 >= 0) { const int r = atomicAdd(&lcur[(p1 >> 17) & 127], 1); lsort[r] = p1 & SRC_MASK; }
        if (p2 >= 0) { const int r = atomicAdd(&lcur[(p2 >> 17) & 127], 1); lsort[r] = p2 & SRC_MASK; }
        if (p3 >= 0) { const int r = atomicAdd(&lcur[(p3 >> 17) & 127], 1); lsort[r] = p3 & SRC_MASK; }
        __syncthreads();
    } else {
        // ---- synthetic setup for loop-only: uniform lbeg, hashed src ids ----
        if (t <= NODES_PER_BKT) lbeg[t] = (t * cnt) >> NBKT_BITS;
        for (int i = t; i < cnt; i += 512) {
            const unsigned h = (unsigned)i * 2654435761u + (unsigned)b * 40503u;
            lsort[i] = (int)(((unsigned long long)h * (unsigned)N) >> 32);
        }
        __syncthreads();
    }

    if (MODE == 1) {
        // keep lsort/lbeg live; scratch writes (overwritten by MODE-0 later)
        float v = (float)lbeg[t & 127];
        if (t < cnt) v += (float)lsort[t];
        out[(size_t)node0 * 64 + t] = v;
        return;
    }

    // ---- phase D: gather loop (r8 shape) ----
    const int wave = t >> 6;
    const int lane = t & 63;
    const int slot = lane >> 4;
    const int part = lane & 15;
    #pragma unroll
    for (int j = 0; j < NODES_PER_BKT / 8; ++j) {
        const int n = wave * (NODES_PER_BKT / 8) + j;
        const int e0 = lbeg[n];
        const int e1 = lbeg[n + 1];
        float4 acc = make_float4(0.f, 0.f, 0.f, 0.f);
        for (int k = e0 + slot; k < e1; k += 4) {
            const int s = lsort[k];
            const float4 v = *reinterpret_cast<const float4*>(feat + (size_t)s * 64 + part * 4);
            acc.x += v.x; acc.y += v.y; acc.z += v.z; acc.w += v.w;
        }
        acc.x += __shfl_xor(acc.x, 16); acc.y += __shfl_xor(acc.y, 16);
        acc.z += __shfl_xor(acc.z, 16); acc.w += __shfl_xor(acc.w, 16);
        acc.x += __shfl_xor(acc.x, 32); acc.y += __shfl_xor(acc.y, 32);
        acc.z += __shfl_xor(acc.z, 32); acc.w += __shfl_xor(acc.w, 32);
        const int g = node0 + n;
        if (slot == 0 && g < N)
            *reinterpret_cast<float4*>(out + (size_t)g * 64 + part * 4) = acc;
    }
}

// ---------- last-resort fallback ----------
__global__ void atomic_fallback_kernel(const float* __restrict__ feat,
                                       const int* __restrict__ src,
                                       const int* __restrict__ dst,
                                       float* __restrict__ out, int E) {
    const int total = E * 16;
    int idx = blockIdx.x * blockDim.x + threadIdx.x;
    const int stride = gridDim.x * blockDim.x;
    for (int i = idx; i < total; i += stride) {
        const int e = i >> 4;
        const int part = i & 15;
        const float4 v = *reinterpret_cast<const float4*>(feat + (size_t)src[e] * 64 + part * 4);
        float* o = out + (size_t)dst[e] * 64 + part * 4;
        unsafeAtomicAdd(o + 0, v.x);
        unsafeAtomicAdd(o + 1, v.y);
        unsafeAtomicAdd(o + 2, v.z);
        unsafeAtomicAdd(o + 3, v.w);
    }
}

extern "C" void kernel_launch(void* const* d_in, const int* in_sizes, int n_in,
                              void* d_out, int out_size, void* d_ws, size_t ws_size,
                              hipStream_t stream) {
    const float* feat = (const float*)d_in[0];
    const int*   src  = (const int*)d_in[1];
    const int*   dst  = (const int*)d_in[2];
    float*       out  = (float*)d_out;
    const int E = in_sizes[1];
    const int N = out_size / 64;                          // 100000
    const int NB = (N + NODES_PER_BKT - 1) >> NBKT_BITS;  // 782
    const int binGrid = (E + BIN_CHUNK - 1) / BIN_CHUNK;  // 293

    const size_t need = ((size_t)NBKT_CAP + (size_t)NB * EDGE_CAP) * sizeof(int);
    const bool shape_ok = (NB <= NBKT_CAP) && (N <= SRC_MASK + 1);

    if (shape_ok && ws_size >= need) {
        int* bcnt   = (int*)d_ws;        // NBKT_CAP
        int* binned = bcnt + NBKT_CAP;   // NB * EDGE_CAP slots
        hipMemsetAsync(bcnt, 0, (size_t)NBKT_CAP * sizeof(int), stream);
        bin_direct_kernel<<<binGrid, 1024, 0, stream>>>(src, dst, bcnt, binned, E, NB);
        // Ablation probes first (their d_out writes are scratch)...
        gather_abl_kernel<1><<<NB, 512, 0, stream>>>(feat, bcnt, binned, out, N);
        gather_abl_kernel<2><<<NB, 512, 0, stream>>>(feat, bcnt, binned, out, N);
        // ...real kernel LAST: writes every d_out element -> output correct.
        gather_abl_kernel<0><<<NB, 512, 0, stream>>>(feat, bcnt, binned, out, N);
    } else {
        hipMemsetAsync(out, 0, (size_t)out_size * sizeof(float), stream);
        int grid = (E * 16 + 255) / 256;
        if (grid > 4096) grid = 4096;
        atomic_fallback_kernel<<<grid, 256, 0, stream>>>(feat, src, dst, out, E);
    }
}